// Round 7
// baseline (767.354 us; speedup 1.0000x reference)
//
#include <hip/hip_runtime.h>
#include <stdint.h>

#define N_ENT 100000
#define N_USR 50000
#define NREG  2597
#define REG0  42033
#define CHAN  128
#define NEDGE 2000000
#define NNZI  1000000

// ---- bucketed CSR build ----
#define BSPAN 512               // heads per bucket (2^9)
#define NB_E  196               // ceil(100000/512)
#define NB_U  98                // ceil(50000/512)
#define BCAP  11264             // slab capacity per bucket (mean 10240, +10 sigma)
#define PKSTR 64                // fixed per-head segment stride (P(deg>64) ~ 1e-15)
#define TILE  2048              // edges per partition WG
#define EPT   8                 // edges per thread (256 thr)
#define NWG_E ((NEDGE + TILE - 1) / TILE)   // 977
#define NWG_U ((NNZI  + TILE - 1) / TILE)   // 489

// ---- region MFMA GEMM geometry ----
#define MT16   163              // ceil(NREG/16) M-tiles
#define MPAD   (MT16 * 16)      // 2608 padded rows
#define KSTEPS 82               // ceil(NREG/32)
#define KPAD   (KSTEPS * 32)    // 2624 padded K
#define NKC2   8                // K-split chunks
#define SPC    ((KSTEPS + NKC2 - 1) / NKC2)  // 11 K-steps per chunk

// ---- fused agg grid: 2:1 entity:user block interleave ----
#define NTRIP  12500            // N_ENT/8 == N_USR/4
#define NBLK_AGG (NTRIP * 3)    // 37500 blocks

typedef unsigned int uint32;
typedef unsigned short ushort16;
using bf16x8 = __attribute__((ext_vector_type(8))) short;   // 8 bf16 (4 VGPRs)
using f32x4  = __attribute__((ext_vector_type(4))) float;   // 4 fp32 acc

__device__ __forceinline__ uint32 f2bf(float x) {
  uint32 b = __float_as_uint(x);
  b += 0x7FFFu + ((b >> 16) & 1u);   // round-to-nearest-even
  return b >> 16;
}
__device__ __forceinline__ float bf_lo(uint32 u) { return __uint_as_float(u << 16); }
__device__ __forceinline__ float bf_hi(uint32 u) { return __uint_as_float(u & 0xFFFF0000u); }

// ---------------- bucketed CSR build ----------------
// Edge staging record (uint32): bits 0..16 tail, 17..21 rel, 22..30 loc(head&511).
// User staging record (uint2): x = valbits, y = col | loc<<17.

__global__ __launch_bounds__(256) void k_part_e(const int* __restrict__ head,
                                                const int* __restrict__ tail,
                                                const int* __restrict__ type,
                                                int* __restrict__ cur,
                                                uint32* __restrict__ st) {
  __shared__ int lh[NB_E], lb[NB_E];
  int tid = threadIdx.x;
  for (int i = tid; i < NB_E; i += 256) lh[i] = 0;
  __syncthreads();
  int base = blockIdx.x * TILE;
  int bk[EPT], rk[EPT]; uint32 rec[EPT];
#pragma unroll
  for (int j = 0; j < EPT; ++j) {
    int idx = base + j * 256 + tid;
    bk[j] = -1;
    if (idx < NEDGE) {
      int h = head[idx];
      uint32 loc = (uint32)(h & (BSPAN - 1));
      rec[j] = (uint32)tail[idx] | ((uint32)(type[idx] - 1) << 17) | (loc << 22);
      bk[j] = h >> 9;
      rk[j] = atomicAdd(&lh[bk[j]], 1);
    }
  }
  __syncthreads();
  for (int i = tid; i < NB_E; i += 256)
    lb[i] = lh[i] ? atomicAdd(&cur[i], lh[i]) : 0;
  __syncthreads();
#pragma unroll
  for (int j = 0; j < EPT; ++j) {
    if (bk[j] >= 0) {
      int slot = lb[bk[j]] + rk[j];
      if (slot < BCAP) st[(size_t)bk[j] * BCAP + slot] = rec[j];   // coalesced runs
    }
  }
}

__global__ __launch_bounds__(256) void k_part_u(const int* __restrict__ rows,
                                                const int* __restrict__ cols,
                                                const float* __restrict__ vals,
                                                int* __restrict__ cur,
                                                uint2* __restrict__ st) {
  __shared__ int lh[NB_U], lb[NB_U];
  int tid = threadIdx.x;
  for (int i = tid; i < NB_U; i += 256) lh[i] = 0;
  __syncthreads();
  int base = blockIdx.x * TILE;
  int bk[EPT], rk[EPT]; uint2 rec[EPT];
#pragma unroll
  for (int j = 0; j < EPT; ++j) {
    int idx = base + j * 256 + tid;
    bk[j] = -1;
    if (idx < NNZI) {
      int r = rows[idx];
      uint32 loc = (uint32)(r & (BSPAN - 1));
      rec[j] = make_uint2(__float_as_uint(vals[idx]), (uint32)cols[idx] | (loc << 17));
      bk[j] = r >> 9;
      rk[j] = atomicAdd(&lh[bk[j]], 1);
    }
  }
  __syncthreads();
  for (int i = tid; i < NB_U; i += 256)
    lb[i] = lh[i] ? atomicAdd(&cur[i], lh[i]) : 0;
  __syncthreads();
#pragma unroll
  for (int j = 0; j < EPT; ++j) {
    if (bk[j] >= 0) {
      int slot = lb[bk[j]] + rk[j];
      if (slot < BCAP) st[(size_t)bk[j] * BCAP + slot] = rec[j];
    }
  }
}

// one WG per bucket: LDS per-head hist -> deg[] + sentinel pad (to x4), then
// rank+place pk into FIXED-STRIDE segments pk[head*PKSTR ...]. No prefix scan.
// Pad slots get sentinel records (rel=25 -> zero weight row / val=0) so the agg
// kernel needs no masks and no bounds checks.
__global__ __launch_bounds__(512) void k_place_e(const uint32* __restrict__ st,
                                                 const int* __restrict__ bcnt,
                                                 int* __restrict__ deg,
                                                 int* __restrict__ pk) {
  __shared__ int hcnt[BSPAN];
  int tid = threadIdx.x;
  int b = blockIdx.x;
  int cnt = bcnt[b]; if (cnt > BCAP) cnt = BCAP;
  int h0 = b << 9;
  hcnt[tid] = 0;
  __syncthreads();
  const uint32* bst = st + (size_t)b * BCAP;
  for (int i = tid; i < cnt; i += 512)
    atomicAdd(&hcnt[(bst[i] >> 22) & (BSPAN - 1)], 1);
  __syncthreads();
  int mycnt = hcnt[tid]; if (mycnt > PKSTR) mycnt = PKSTR;
  int mypad = (mycnt + 3) & ~3;
  int gh = h0 + tid;
  if (gh < N_ENT) {
    deg[gh] = mycnt;
    for (int j = mycnt; j < mypad; ++j) pk[(size_t)gh * PKSTR + j] = (25 << 17);
  }
  __syncthreads();
  hcnt[tid] = 0;
  __syncthreads();
  for (int i = tid; i < cnt; i += 512) {
    uint32 r = bst[i];
    int loc = (r >> 22) & (BSPAN - 1);
    int rk = atomicAdd(&hcnt[loc], 1);
    if (rk < PKSTR)
      pk[(size_t)(h0 + loc) * PKSTR + rk] = (int)(r & 0x3FFFFFu);  // tail | rel<<17
  }
}

__global__ __launch_bounds__(512) void k_place_u(const uint2* __restrict__ st,
                                                 const int* __restrict__ bcnt,
                                                 int* __restrict__ deg,
                                                 int2* __restrict__ pk) {
  __shared__ int hcnt[BSPAN];
  int tid = threadIdx.x;
  int b = blockIdx.x;
  int cnt = bcnt[b]; if (cnt > BCAP) cnt = BCAP;
  int h0 = b << 9;
  hcnt[tid] = 0;
  __syncthreads();
  const uint2* bst = st + (size_t)b * BCAP;
  for (int i = tid; i < cnt; i += 512)
    atomicAdd(&hcnt[bst[i].y >> 17], 1);
  __syncthreads();
  int mycnt = hcnt[tid]; if (mycnt > PKSTR) mycnt = PKSTR;
  int mypad = (mycnt + 3) & ~3;
  int gh = h0 + tid;
  if (gh < N_USR) {
    deg[gh] = mycnt;
    for (int j = mycnt; j < mypad; ++j) pk[(size_t)gh * PKSTR + j] = make_int2(0, 0);
  }
  __syncthreads();
  hcnt[tid] = 0;
  __syncthreads();
  for (int i = tid; i < cnt; i += 512) {
    uint2 r = bst[i];
    int loc = r.y >> 17;
    int rk = atomicAdd(&hcnt[loc], 1);
    if (rk < PKSTR)
      pk[(size_t)(h0 + loc) * PKSTR + rk] = make_int2((int)(r.y & 0x1FFFFu), (int)r.x);
  }
}

// ---------------- weight table + zero sentinel row (row 25) ----------------
__global__ void k_wt26(const float* __restrict__ w, float* __restrict__ wt) {
  int i = blockIdx.x * blockDim.x + threadIdx.x;
  if (i < 26 * CHAN) wt[i] = (i < 25 * CHAN) ? w[i] : 0.f;
}

// ---------------- fused init: entity fp32 -> bf16 table + out_e + region Rf ----------------
__global__ void k_init_ent(const float* __restrict__ src, uint32* __restrict__ dstB,
                           float* __restrict__ out_e, float* __restrict__ Rf) {
  int i = blockIdx.x * blockDim.x + threadIdx.x;   // over N_ENT*CHAN/8
  if (i >= N_ENT * CHAN / 8) return;
  size_t o = (size_t)i * 8;
  float4 v0 = *(const float4*)(src + o);
  float4 v1 = *(const float4*)(src + o + 4);
  uint4 b;
  b.x = f2bf(v0.x) | (f2bf(v0.y) << 16);
  b.y = f2bf(v0.z) | (f2bf(v0.w) << 16);
  b.z = f2bf(v1.x) | (f2bf(v1.y) << 16);
  b.w = f2bf(v1.z) | (f2bf(v1.w) << 16);
  *(uint4*)(dstB + (size_t)i * 4) = b;
  *(float4*)(out_e + o) = v0;
  *(float4*)(out_e + o + 4) = v1;
  int h = (int)(o >> 7);
  if (h >= REG0 && h < REG0 + NREG) {
    size_t ro = (((size_t)(h - REG0)) << 7) + (o & 127);
    *(float4*)(Rf + ro) = v0;
    *(float4*)(Rf + ro + 4) = v1;
  }
}

// ---------------- RW (fp32, pitch NREG) -> RWb bf16 [MPAD][KPAD], zero-padded ----------------
__global__ void k_cast_rwb(const float* __restrict__ RW, uint32* __restrict__ RWb) {
  int i = blockIdx.x * blockDim.x + threadIdx.x;     // over MPAD * KPAD/8
  if (i >= MPAD * (KPAD / 8)) return;
  int r = i / (KPAD / 8);
  int k0 = (i % (KPAD / 8)) * 8;
  uint32 o[4];
  if (r < NREG) {
    const float* s = RW + (size_t)r * NREG;
#pragma unroll
    for (int j = 0; j < 4; ++j) {
      int ka = k0 + 2 * j, kb = ka + 1;
      float va = (ka < NREG) ? s[ka] : 0.f;
      float vb = (kb < NREG) ? s[kb] : 0.f;
      o[j] = f2bf(va) | (f2bf(vb) << 16);
    }
  } else {
    o[0] = o[1] = o[2] = o[3] = 0u;
  }
  *(uint4*)(RWb + (size_t)r * (KPAD / 2) + k0 / 2) = make_uint4(o[0], o[1], o[2], o[3]);
}

// ---------------- per hop: curR [NREG][128] fp32 -> RbT bf16 [128][KPAD] (transposed) ----------------
__global__ void k_build_rbt(const float* __restrict__ Rf, uint32* __restrict__ RbT) {
  int i = blockIdx.x * blockDim.x + threadIdx.x;     // over CHAN * KPAD/8
  if (i >= CHAN * (KPAD / 8)) return;
  int c = i / (KPAD / 8);
  int k0 = (i % (KPAD / 8)) * 8;
  uint32 o[4];
#pragma unroll
  for (int j = 0; j < 4; ++j) {
    int ka = k0 + 2 * j, kb = ka + 1;
    float va = (ka < NREG) ? Rf[(size_t)ka * CHAN + c] : 0.f;
    float vb = (kb < NREG) ? Rf[(size_t)kb * CHAN + c] : 0.f;
    o[j] = f2bf(va) | (f2bf(vb) << 16);
  }
  *(uint4*)(RbT + (size_t)c * (KPAD / 2) + k0 / 2) = make_uint4(o[0], o[1], o[2], o[3]);
}

// ---------------- region GEMM on matrix cores (split output, no atomics) ----------------
__global__ __launch_bounds__(256) void k_region_mfma(const ushort16* __restrict__ RWb,
                                                     const ushort16* __restrict__ RbT,
                                                     float* __restrict__ Rtmp8) {
  int lane = threadIdx.x & 63;
  int wid  = threadIdx.x >> 6;          // 0..3
  int mt = blockIdx.x % MT16;
  int kc = blockIdx.x / MT16;
  int m0 = mt * 16;
  int rc  = lane & 15;                  // A-row / B-col index within tile
  int kq  = lane >> 4;                  // 0..3

  int s0 = kc * SPC;
  int s1 = s0 + SPC; if (s1 > KSTEPS) s1 = KSTEPS;

  f32x4 acc0 = {0.f, 0.f, 0.f, 0.f};
  f32x4 acc1 = {0.f, 0.f, 0.f, 0.f};

  const ushort16* arow = RWb + (size_t)(m0 + rc) * KPAD;
  const ushort16* b0   = RbT + (size_t)(wid * 32 + rc) * KPAD;
  const ushort16* b1   = b0 + (size_t)16 * KPAD;

  for (int s = s0; s < s1; ++s) {
    int k = s * 32 + kq * 8;
    bf16x8 a  = *(const bf16x8*)(arow + k);
    bf16x8 v0 = *(const bf16x8*)(b0 + k);
    bf16x8 v1 = *(const bf16x8*)(b1 + k);
    acc0 = __builtin_amdgcn_mfma_f32_16x16x32_bf16(a, v0, acc0, 0, 0, 0);
    acc1 = __builtin_amdgcn_mfma_f32_16x16x32_bf16(a, v1, acc1, 0, 0, 0);
  }

  float* dst = Rtmp8 + (size_t)kc * (NREG * CHAN);
  int orow = m0 + kq * 4;
#pragma unroll
  for (int r = 0; r < 4; ++r) {
    int gr = orow + r;
    if (gr < NREG) {
      dst[(size_t)gr * CHAN + wid * 32 + rc]      = acc0[r];
      dst[(size_t)gr * CHAN + wid * 32 + 16 + rc] = acc1[r];
    }
  }
}

// Rf = 0.8*Rf + 0.2*sum(Rtmp8 slices) ; mirror region rows into bf16 gather table
__global__ void k_region_apply(float* __restrict__ Rf, const float* __restrict__ Rtmp8,
                               ushort16* __restrict__ curB) {
  int i = blockIdx.x * blockDim.x + threadIdx.x;
  if (i < NREG * CHAN) {
    float t = 0.f;
#pragma unroll
    for (int c = 0; c < NKC2; ++c) t += Rtmp8[(size_t)c * (NREG * CHAN) + i];
    float v = Rf[i] * 0.8f + t * 0.2f;
    Rf[i] = v;
    curB[(size_t)REG0 * CHAN + i] = (ushort16)f2bf(v);
  }
}

// ---------------- fused agg: entity + user waves co-resident ----------------
// Fixed-stride maskless CSR: pk[h*64 + slot], deg[h]. The deg load and the
// pk batch load are INDEPENDENT (both address off h) -> issue in parallel,
// cutting one ~600cy level out of the per-wave serial prologue chain.
// inv_deg dropped entirely: l2_normalize is scale-invariant (deg=0 -> acc=0 -> 0).
// nch <= 16 by construction -> no batch refresh. Segments padded to x4 with
// sentinels (rel=25 zero-weight row / val=0) -> no masks, no bounds checks.
// All shuffles UNCONDITIONAL within wave-uniform branches (round-1 lesson).

__global__ __launch_bounds__(256) void k_agg(
    const ushort16* __restrict__ curB,
    const int* __restrict__ edeg, const int* __restrict__ epk,
    const float* __restrict__ Wt,
    uint32* __restrict__ nxtB, float* __restrict__ nxtRf, float* __restrict__ out_e,
    const int* __restrict__ udeg, const int2* __restrict__ upk,
    float* __restrict__ out_u) {
  int bid  = blockIdx.x;
  int wid  = threadIdx.x >> 6;
  int lane = threadIdx.x & 63;
  int grp  = bid % 3;
  int trip = bid / 3;
  int e = lane >> 4;
  int q = lane & 15;

  if (grp < 2) {
    // ---------------- entity wave ----------------
    int h = trip * 8 + grp * 4 + wid;            // < 100000
    int nch = (edeg[h] + 3) >> 2;                // parallel with pkv load below
    int pkv = epk[(size_t)h * PKSTR + lane];     // unconditional, coalesced 256B

    float acc[8];
#pragma unroll
    for (int k = 0; k < 8; ++k) acc[k] = 0.f;

    uint4  evA = make_uint4(0, 0, 0, 0);
    float4 waA = make_float4(0.f, 0.f, 0.f, 0.f);
    float4 wbA = make_float4(0.f, 0.f, 0.f, 0.f);

    {  // prologue: issue chunk 0 (slots always readable; consumed only if nch>0)
      int p = __shfl(pkv, e, 64);
      int t = p & 0x1FFFF;
      int r = p >> 17;
      evA = *(const uint4*)((const char*)curB + ((size_t)t << 8) + (q << 4));
      const float* wr = Wt + ((size_t)r << 7) + (q << 3);
      waA = *(const float4*)wr;
      wbA = *(const float4*)(wr + 4);
    }

    for (int ci = 0; ci < nch; ++ci) {
      uint4  evB = make_uint4(0, 0, 0, 0);
      float4 waB = make_float4(0.f, 0.f, 0.f, 0.f);
      float4 wbB = make_float4(0.f, 0.f, 0.f, 0.f);
      int cn = ci + 1;
      if (cn < nch) {
        int p = __shfl(pkv, (cn << 2) | e, 64);
        int t = p & 0x1FFFF;
        int r = p >> 17;
        evB = *(const uint4*)((const char*)curB + ((size_t)t << 8) + (q << 4));
        const float* wr = Wt + ((size_t)r << 7) + (q << 3);
        waB = *(const float4*)wr;
        wbB = *(const float4*)(wr + 4);
      }
      acc[0] += bf_lo(evA.x) * waA.x;
      acc[1] += bf_hi(evA.x) * waA.y;
      acc[2] += bf_lo(evA.y) * waA.z;
      acc[3] += bf_hi(evA.y) * waA.w;
      acc[4] += bf_lo(evA.z) * wbA.x;
      acc[5] += bf_hi(evA.z) * wbA.y;
      acc[6] += bf_lo(evA.w) * wbA.z;
      acc[7] += bf_hi(evA.w) * wbA.w;
      evA = evB; waA = waB; wbA = wbB;
    }

#pragma unroll
    for (int k = 0; k < 8; ++k) {
      acc[k] += __shfl_xor(acc[k], 16, 64);
      acc[k] += __shfl_xor(acc[k], 32, 64);
    }
    float ss = 0.f;
#pragma unroll
    for (int k = 0; k < 8; ++k) ss += acc[k] * acc[k];
#pragma unroll
    for (int off = 8; off; off >>= 1) ss += __shfl_xor(ss, off, 64);
    float inv = 1.0f / fmaxf(sqrtf(ss), 1e-12f);
#pragma unroll
    for (int k = 0; k < 8; ++k) acc[k] *= inv;

    if (e == 0) {   // 16 lanes cover the full 128-channel row
      uint4 bpk;
      bpk.x = f2bf(acc[0]) | (f2bf(acc[1]) << 16);
      bpk.y = f2bf(acc[2]) | (f2bf(acc[3]) << 16);
      bpk.z = f2bf(acc[4]) | (f2bf(acc[5]) << 16);
      bpk.w = f2bf(acc[6]) | (f2bf(acc[7]) << 16);
      *(uint4*)((char*)nxtB + ((size_t)h << 8) + (q << 4)) = bpk;
      if (h >= REG0 && h < REG0 + NREG) {
        float* rp = nxtRf + ((size_t)(h - REG0) << 7) + (q << 3);
        *(float4*)rp       = make_float4(acc[0], acc[1], acc[2], acc[3]);
        *(float4*)(rp + 4) = make_float4(acc[4], acc[5], acc[6], acc[7]);
      }
      float* op = out_e + ((size_t)h << 7) + (q << 3);
      float4 o0 = *(const float4*)op;
      float4 o1 = *(const float4*)(op + 4);
      o0.x += acc[0]; o0.y += acc[1]; o0.z += acc[2]; o0.w += acc[3];
      o1.x += acc[4]; o1.y += acc[5]; o1.z += acc[6]; o1.w += acc[7];
      *(float4*)op       = o0;
      *(float4*)(op + 4) = o1;
    }
  } else {
    // ---------------- user wave ----------------
    int u = trip * 4 + wid;                     // < 50000
    int nch = (udeg[u] + 3) >> 2;               // parallel with pkv load below
    int2 pkv = upk[(size_t)u * PKSTR + lane];   // unconditional, coalesced 512B

    float acc[8];
#pragma unroll
    for (int k = 0; k < 8; ++k) acc[k] = 0.f;

    uint4 evA = make_uint4(0, 0, 0, 0);
    float vA = 0.f;

    {  // prologue
      int col = __shfl(pkv.x, e, 64);
      vA      = __int_as_float(__shfl(pkv.y, e, 64));
      evA = *(const uint4*)((const char*)curB + ((size_t)col << 8) + (q << 4));
    }

    for (int ci = 0; ci < nch; ++ci) {
      uint4 evB = make_uint4(0, 0, 0, 0);
      float vB = 0.f;
      int cn = ci + 1;
      if (cn < nch) {
        int sl = (cn << 2) | e;
        int col = __shfl(pkv.x, sl, 64);
        vB      = __int_as_float(__shfl(pkv.y, sl, 64));
        evB = *(const uint4*)((const char*)curB + ((size_t)col << 8) + (q << 4));
      }
      acc[0] += vA * bf_lo(evA.x);
      acc[1] += vA * bf_hi(evA.x);
      acc[2] += vA * bf_lo(evA.y);
      acc[3] += vA * bf_hi(evA.y);
      acc[4] += vA * bf_lo(evA.z);
      acc[5] += vA * bf_hi(evA.z);
      acc[6] += vA * bf_lo(evA.w);
      acc[7] += vA * bf_hi(evA.w);
      evA = evB; vA = vB;
    }

#pragma unroll
    for (int k = 0; k < 8; ++k) {
      acc[k] += __shfl_xor(acc[k], 16, 64);
      acc[k] += __shfl_xor(acc[k], 32, 64);
    }
    float ss = 0.f;
#pragma unroll
    for (int k = 0; k < 8; ++k) ss += acc[k] * acc[k];
#pragma unroll
    for (int off = 8; off; off >>= 1) ss += __shfl_xor(ss, off, 64);
    float inv = 1.0f / fmaxf(sqrtf(ss), 1e-12f);
#pragma unroll
    for (int k = 0; k < 8; ++k) acc[k] *= inv;

    if (e == 0) {
      float* op = out_u + ((size_t)u << 7) + (q << 3);
      float4 o0 = *(const float4*)op;
      float4 o1 = *(const float4*)(op + 4);
      o0.x += acc[0]; o0.y += acc[1]; o0.z += acc[2]; o0.w += acc[3];
      o1.x += acc[4]; o1.y += acc[5]; o1.z += acc[6]; o1.w += acc[7];
      *(float4*)op       = o0;
      *(float4*)(op + 4) = o1;
    }
  }
}

// ---------------- launch ----------------

extern "C" void kernel_launch(void* const* d_in, const int* in_sizes, int n_in,
                              void* d_out, int out_size, void* d_ws, size_t ws_size,
                              hipStream_t stream) {
  const float* user_emb   = (const float*)d_in[0];
  const float* entity_emb = (const float*)d_in[1];
  const float* RW         = (const float*)d_in[2];
  const float* weight     = (const float*)d_in[3];
  const float* ivals      = (const float*)d_in[4];
  const int*   e_head     = (const int*)d_in[5];
  const int*   e_tail     = (const int*)d_in[6];
  const int*   e_type     = (const int*)d_in[7];
  const int*   i_rows     = (const int*)d_in[8];
  const int*   i_cols     = (const int*)d_in[9];

  float* out_e = (float*)d_out;                        // [N_ENT, 128]
  float* out_u = (float*)d_out + (size_t)N_ENT * CHAN; // [N_USR, 128]

  char* p = (char*)d_ws;
  size_t off = 0;
  auto carve = [&](size_t bytes) -> void* {
    void* r = p + off;
    off += (bytes + 255) & ~(size_t)255;
    return r;
  };
  ushort16* B16a   = (ushort16*)carve((size_t)N_ENT * CHAN * 2);
  ushort16* B16b   = (ushort16*)carve((size_t)N_ENT * CHAN * 2);
  ushort16* RWb    = (ushort16*)carve((size_t)MPAD * KPAD * 2);   // 13.7 MB bf16 weights
  ushort16* RbT    = (ushort16*)carve((size_t)CHAN * KPAD * 2);   // transposed bf16 X
  float* Rfa       = (float*)carve((size_t)NREG * CHAN * 4);
  float* Rfb       = (float*)carve((size_t)NREG * CHAN * 4);
  float* wt26      = (float*)carve((size_t)26 * CHAN * 4);
  int*   e_deg     = (int*)carve((size_t)N_ENT * 4);
  int*   u_deg     = (int*)carve((size_t)N_USR * 4);
  int*   e_pk      = (int*)carve((size_t)N_ENT * PKSTR * 4);      // 25.6 MB
  int2*  u_pk      = (int2*)carve((size_t)N_USR * PKSTR * 8);     // 25.6 MB
  // shared region: CSR staging slab (build phase) OVERLAYS Rtmp8 (hop phase)
  size_t st_bytes   = (size_t)NB_E * BCAP * 4 > (size_t)NB_U * BCAP * 8
                      ? (size_t)NB_E * BCAP * 4 : (size_t)NB_U * BCAP * 8;
  size_t rtmp_bytes = (size_t)NKC2 * NREG * CHAN * 4;
  char*  shared_rg = (char*)carve(st_bytes > rtmp_bytes ? st_bytes : rtmp_bytes);
  float* Rtmp8     = (float*)shared_rg;
  int*   e_bcur    = (int*)carve((size_t)NB_E * 4);
  int*   u_bcur    = (int*)carve((size_t)NB_U * 4);
  if (off > ws_size) return;

  // ---- CSR for edges (bucketed multisplit, fixed-stride maskless segments) ----
  hipMemsetAsync(e_bcur, 0, (size_t)NB_E * 4, stream);
  k_part_e<<<NWG_E, 256, 0, stream>>>(e_head, e_tail, e_type, e_bcur, (uint32*)shared_rg);
  k_place_e<<<NB_E, 512, 0, stream>>>((const uint32*)shared_rg, e_bcur, e_deg, e_pk);

  // ---- CSR for interactions (reuses staging slab; stream order serializes) ----
  hipMemsetAsync(u_bcur, 0, (size_t)NB_U * 4, stream);
  k_part_u<<<NWG_U, 256, 0, stream>>>(i_rows, i_cols, ivals, u_bcur, (uint2*)shared_rg);
  k_place_u<<<NB_U, 512, 0, stream>>>((const uint2*)shared_rg, u_bcur, u_deg, u_pk);

  // ---- init ----
  k_cast_rwb<<<(MPAD * (KPAD / 8) + 255) / 256, 256, 0, stream>>>(RW, (uint32*)RWb);
  k_wt26<<<(26 * CHAN + 255) / 256, 256, 0, stream>>>(weight, wt26);
  k_init_ent<<<(N_ENT * CHAN / 8 + 255) / 256, 256, 0, stream>>>(
      entity_emb, (uint32*)B16a, out_e, Rfa);
  hipMemcpyAsync(out_u, user_emb, (size_t)N_USR * CHAN * 4, hipMemcpyDeviceToDevice, stream);

  // ---- 3 hops ----
  for (int hop = 0; hop < 3; ++hop) {
    ushort16* curB = (hop & 1) ? B16b : B16a;
    ushort16* nxtB = (hop & 1) ? B16a : B16b;
    float*    curR = (hop & 1) ? Rfb : Rfa;
    float*    nxtR = (hop & 1) ? Rfa : Rfb;
    k_build_rbt<<<(CHAN * (KPAD / 8) + 255) / 256, 256, 0, stream>>>(curR, (uint32*)RbT);
    k_region_mfma<<<MT16 * NKC2, 256, 0, stream>>>(RWb, RbT, Rtmp8);
    k_region_apply<<<(NREG * CHAN + 255) / 256, 256, 0, stream>>>(curR, Rtmp8, curB);
    k_agg<<<NBLK_AGG, 256, 0, stream>>>(curB, e_deg, e_pk, wt26,
                                        (uint32*)nxtB, nxtR, out_e,
                                        u_deg, u_pk, out_u);
  }
}

// Round 8
// 749.397 us; speedup vs baseline: 1.0240x; 1.0240x over previous
//
#include <hip/hip_runtime.h>
#include <stdint.h>

#define N_ENT 100000
#define N_USR 50000
#define NREG  2597
#define REG0  42033
#define CHAN  128
#define NEDGE 2000000
#define NNZI  1000000

// ---- bucketed CSR build ----
#define BSPAN 512               // heads per bucket (2^9)
#define NB_E  196               // ceil(100000/512)
#define NB_U  98                // ceil(50000/512)
#define BCAP  11264             // slab capacity per bucket (mean 10240, +10 sigma)
#define PKSTR 64                // fixed per-head segment stride (P(deg>64) ~ 1e-15)
#define TILE  2048              // edges per partition WG
#define EPT   8                 // edges per thread (256 thr)
#define NWG_E ((NEDGE + TILE - 1) / TILE)   // 977
#define NWG_U ((NNZI  + TILE - 1) / TILE)   // 489

// ---- region MFMA GEMM geometry ----
#define MT16   163              // ceil(NREG/16) M-tiles
#define MPAD   (MT16 * 16)      // 2608 padded rows
#define KSTEPS 82               // ceil(NREG/32)
#define KPAD   (KSTEPS * 32)    // 2624 padded K
#define NKC2   8                // K-split chunks
#define SPC    ((KSTEPS + NKC2 - 1) / NKC2)  // 11 K-steps per chunk

// ---- fused agg grid: 2:1 entity:user block interleave ----
#define NTRIP  12500            // N_ENT/8 == N_USR/4
#define NBLK_AGG (NTRIP * 3)    // 37500 blocks

// ---- fused init grid ranges ----
#define G_RWB  ((MPAD * (KPAD / 8) + 255) / 256)     // 3342
#define G_WT   13                                     // 26*128/256
#define G_IE   ((N_ENT * CHAN / 8) / 256)             // 6250
#define G_CU   ((N_USR * CHAN / 8) / 256)             // 3125
#define G_INIT (G_RWB + G_WT + G_IE + G_CU)

typedef unsigned int uint32;
typedef unsigned short ushort16;
using bf16x8 = __attribute__((ext_vector_type(8))) short;   // 8 bf16 (4 VGPRs)
using f32x4  = __attribute__((ext_vector_type(4))) float;   // 4 fp32 acc

__device__ __forceinline__ uint32 f2bf(float x) {
  uint32 b = __float_as_uint(x);
  b += 0x7FFFu + ((b >> 16) & 1u);   // round-to-nearest-even
  return b >> 16;
}
__device__ __forceinline__ float bf_lo(uint32 u) { return __uint_as_float(u << 16); }
__device__ __forceinline__ float bf_hi(uint32 u) { return __uint_as_float(u & 0xFFFF0000u); }

// ---------------- bucketed CSR build ----------------
// Edge staging record (uint32): bits 0..16 tail, 17..21 rel, 22..30 loc(head&511).
// User staging record (uint2): x = valbits, y = col | loc<<17.

__global__ __launch_bounds__(256) void k_part_e(const int* __restrict__ head,
                                                const int* __restrict__ tail,
                                                const int* __restrict__ type,
                                                int* __restrict__ cur,
                                                uint32* __restrict__ st) {
  __shared__ int lh[NB_E], lb[NB_E];
  int tid = threadIdx.x;
  for (int i = tid; i < NB_E; i += 256) lh[i] = 0;
  __syncthreads();
  int base = blockIdx.x * TILE;
  int bk[EPT], rk[EPT]; uint32 rec[EPT];
#pragma unroll
  for (int j = 0; j < EPT; ++j) {
    int idx = base + j * 256 + tid;
    bk[j] = -1;
    if (idx < NEDGE) {
      int h = head[idx];
      uint32 loc = (uint32)(h & (BSPAN - 1));
      rec[j] = (uint32)tail[idx] | ((uint32)(type[idx] - 1) << 17) | (loc << 22);
      bk[j] = h >> 9;
      rk[j] = atomicAdd(&lh[bk[j]], 1);
    }
  }
  __syncthreads();
  for (int i = tid; i < NB_E; i += 256)
    lb[i] = lh[i] ? atomicAdd(&cur[i], lh[i]) : 0;
  __syncthreads();
#pragma unroll
  for (int j = 0; j < EPT; ++j) {
    if (bk[j] >= 0) {
      int slot = lb[bk[j]] + rk[j];
      if (slot < BCAP) st[(size_t)bk[j] * BCAP + slot] = rec[j];   // coalesced runs
    }
  }
}

__global__ __launch_bounds__(256) void k_part_u(const int* __restrict__ rows,
                                                const int* __restrict__ cols,
                                                const float* __restrict__ vals,
                                                int* __restrict__ cur,
                                                uint2* __restrict__ st) {
  __shared__ int lh[NB_U], lb[NB_U];
  int tid = threadIdx.x;
  for (int i = tid; i < NB_U; i += 256) lh[i] = 0;
  __syncthreads();
  int base = blockIdx.x * TILE;
  int bk[EPT], rk[EPT]; uint2 rec[EPT];
#pragma unroll
  for (int j = 0; j < EPT; ++j) {
    int idx = base + j * 256 + tid;
    bk[j] = -1;
    if (idx < NNZI) {
      int r = rows[idx];
      uint32 loc = (uint32)(r & (BSPAN - 1));
      rec[j] = make_uint2(__float_as_uint(vals[idx]), (uint32)cols[idx] | (loc << 17));
      bk[j] = r >> 9;
      rk[j] = atomicAdd(&lh[bk[j]], 1);
    }
  }
  __syncthreads();
  for (int i = tid; i < NB_U; i += 256)
    lb[i] = lh[i] ? atomicAdd(&cur[i], lh[i]) : 0;
  __syncthreads();
#pragma unroll
  for (int j = 0; j < EPT; ++j) {
    if (bk[j] >= 0) {
      int slot = lb[bk[j]] + rk[j];
      if (slot < BCAP) st[(size_t)bk[j] * BCAP + slot] = rec[j];
    }
  }
}

// one WG per bucket: LDS per-head hist -> deg[] + sentinel pad (to x4), then
// rank+place pk into FIXED-STRIDE segments pk[head*PKSTR ...]. No prefix scan.
// Pad slots get sentinel records (rel=25 -> zero weight row / val=0) so the agg
// kernel needs no masks and no bounds checks.
__global__ __launch_bounds__(512) void k_place_e(const uint32* __restrict__ st,
                                                 const int* __restrict__ bcnt,
                                                 int* __restrict__ deg,
                                                 int* __restrict__ pk) {
  __shared__ int hcnt[BSPAN];
  int tid = threadIdx.x;
  int b = blockIdx.x;
  int cnt = bcnt[b]; if (cnt > BCAP) cnt = BCAP;
  int h0 = b << 9;
  hcnt[tid] = 0;
  __syncthreads();
  const uint32* bst = st + (size_t)b * BCAP;
  for (int i = tid; i < cnt; i += 512)
    atomicAdd(&hcnt[(bst[i] >> 22) & (BSPAN - 1)], 1);
  __syncthreads();
  int mycnt = hcnt[tid]; if (mycnt > PKSTR) mycnt = PKSTR;
  int mypad = (mycnt + 3) & ~3;
  int gh = h0 + tid;
  if (gh < N_ENT) {
    deg[gh] = mycnt;
    for (int j = mycnt; j < mypad; ++j) pk[(size_t)gh * PKSTR + j] = (25 << 17);
  }
  __syncthreads();
  hcnt[tid] = 0;
  __syncthreads();
  for (int i = tid; i < cnt; i += 512) {
    uint32 r = bst[i];
    int loc = (r >> 22) & (BSPAN - 1);
    int rk = atomicAdd(&hcnt[loc], 1);
    if (rk < PKSTR)
      pk[(size_t)(h0 + loc) * PKSTR + rk] = (int)(r & 0x3FFFFFu);  // tail | rel<<17
  }
}

__global__ __launch_bounds__(512) void k_place_u(const uint2* __restrict__ st,
                                                 const int* __restrict__ bcnt,
                                                 int* __restrict__ deg,
                                                 int2* __restrict__ pk) {
  __shared__ int hcnt[BSPAN];
  int tid = threadIdx.x;
  int b = blockIdx.x;
  int cnt = bcnt[b]; if (cnt > BCAP) cnt = BCAP;
  int h0 = b << 9;
  hcnt[tid] = 0;
  __syncthreads();
  const uint2* bst = st + (size_t)b * BCAP;
  for (int i = tid; i < cnt; i += 512)
    atomicAdd(&hcnt[bst[i].y >> 17], 1);
  __syncthreads();
  int mycnt = hcnt[tid]; if (mycnt > PKSTR) mycnt = PKSTR;
  int mypad = (mycnt + 3) & ~3;
  int gh = h0 + tid;
  if (gh < N_USR) {
    deg[gh] = mycnt;
    for (int j = mycnt; j < mypad; ++j) pk[(size_t)gh * PKSTR + j] = make_int2(0, 0);
  }
  __syncthreads();
  hcnt[tid] = 0;
  __syncthreads();
  for (int i = tid; i < cnt; i += 512) {
    uint2 r = bst[i];
    int loc = r.y >> 17;
    int rk = atomicAdd(&hcnt[loc], 1);
    if (rk < PKSTR)
      pk[(size_t)(h0 + loc) * PKSTR + rk] = make_int2((int)(r.y & 0x1FFFFu), (int)r.x);
  }
}

// ---------------- fused init: RW->bf16, wt26, entity init, user out copy ----------------
__global__ __launch_bounds__(256) void k_init(const float* __restrict__ RW,
                                              uint32* __restrict__ RWb,
                                              const float* __restrict__ w,
                                              float* __restrict__ wt,
                                              const float* __restrict__ esrc,
                                              uint32* __restrict__ dstB,
                                              float* __restrict__ out_e,
                                              float* __restrict__ Rf,
                                              const float* __restrict__ usrc,
                                              float* __restrict__ out_u) {
  int b = blockIdx.x;
  int tid = threadIdx.x;
  if (b < G_RWB) {
    // RW (fp32, pitch NREG) -> RWb bf16 [MPAD][KPAD], zero-padded
    int i = b * 256 + tid;
    if (i >= MPAD * (KPAD / 8)) return;
    int r = i / (KPAD / 8);
    int k0 = (i % (KPAD / 8)) * 8;
    uint32 o[4];
    if (r < NREG) {
      const float* s = RW + (size_t)r * NREG;
#pragma unroll
      for (int j = 0; j < 4; ++j) {
        int ka = k0 + 2 * j, kb = ka + 1;
        float va = (ka < NREG) ? s[ka] : 0.f;
        float vb = (kb < NREG) ? s[kb] : 0.f;
        o[j] = f2bf(va) | (f2bf(vb) << 16);
      }
    } else {
      o[0] = o[1] = o[2] = o[3] = 0u;
    }
    *(uint4*)(RWb + (size_t)r * (KPAD / 2) + k0 / 2) = make_uint4(o[0], o[1], o[2], o[3]);
  } else if (b < G_RWB + G_WT) {
    // weight table + zero sentinel row (row 25)
    int i = (b - G_RWB) * 256 + tid;
    if (i < 26 * CHAN) wt[i] = (i < 25 * CHAN) ? w[i] : 0.f;
  } else if (b < G_RWB + G_WT + G_IE) {
    // entity fp32 -> bf16 table + out_e + region Rf
    int i = (b - G_RWB - G_WT) * 256 + tid;
    size_t o = (size_t)i * 8;
    float4 v0 = *(const float4*)(esrc + o);
    float4 v1 = *(const float4*)(esrc + o + 4);
    uint4 bb;
    bb.x = f2bf(v0.x) | (f2bf(v0.y) << 16);
    bb.y = f2bf(v0.z) | (f2bf(v0.w) << 16);
    bb.z = f2bf(v1.x) | (f2bf(v1.y) << 16);
    bb.w = f2bf(v1.z) | (f2bf(v1.w) << 16);
    *(uint4*)(dstB + (size_t)i * 4) = bb;
    *(float4*)(out_e + o) = v0;
    *(float4*)(out_e + o + 4) = v1;
    int h = (int)(o >> 7);
    if (h >= REG0 && h < REG0 + NREG) {
      size_t ro = (((size_t)(h - REG0)) << 7) + (o & 127);
      *(float4*)(Rf + ro) = v0;
      *(float4*)(Rf + ro + 4) = v1;
    }
  } else {
    // user_emb -> out_u copy
    int i = (b - G_RWB - G_WT - G_IE) * 256 + tid;
    size_t o = (size_t)i * 8;
    float4 v0 = *(const float4*)(usrc + o);
    float4 v1 = *(const float4*)(usrc + o + 4);
    *(float4*)(out_u + o) = v0;
    *(float4*)(out_u + o + 4) = v1;
  }
}

// ---------------- per hop: curR [NREG][128] fp32 -> RbT bf16 [128][KPAD] (transposed) ----------------
__global__ void k_build_rbt(const float* __restrict__ Rf, uint32* __restrict__ RbT) {
  int i = blockIdx.x * blockDim.x + threadIdx.x;     // over CHAN * KPAD/8
  if (i >= CHAN * (KPAD / 8)) return;
  int c = i / (KPAD / 8);
  int k0 = (i % (KPAD / 8)) * 8;
  uint32 o[4];
#pragma unroll
  for (int j = 0; j < 4; ++j) {
    int ka = k0 + 2 * j, kb = ka + 1;
    float va = (ka < NREG) ? Rf[(size_t)ka * CHAN + c] : 0.f;
    float vb = (kb < NREG) ? Rf[(size_t)kb * CHAN + c] : 0.f;
    o[j] = f2bf(va) | (f2bf(vb) << 16);
  }
  *(uint4*)(RbT + (size_t)c * (KPAD / 2) + k0 / 2) = make_uint4(o[0], o[1], o[2], o[3]);
}

// ---------------- region GEMM on matrix cores (split output, no atomics) ----------------
__global__ __launch_bounds__(256) void k_region_mfma(const ushort16* __restrict__ RWb,
                                                     const ushort16* __restrict__ RbT,
                                                     float* __restrict__ Rtmp8) {
  int lane = threadIdx.x & 63;
  int wid  = threadIdx.x >> 6;          // 0..3
  int mt = blockIdx.x % MT16;
  int kc = blockIdx.x / MT16;
  int m0 = mt * 16;
  int rc  = lane & 15;                  // A-row / B-col index within tile
  int kq  = lane >> 4;                  // 0..3

  int s0 = kc * SPC;
  int s1 = s0 + SPC; if (s1 > KSTEPS) s1 = KSTEPS;

  f32x4 acc0 = {0.f, 0.f, 0.f, 0.f};
  f32x4 acc1 = {0.f, 0.f, 0.f, 0.f};

  const ushort16* arow = RWb + (size_t)(m0 + rc) * KPAD;
  const ushort16* b0   = RbT + (size_t)(wid * 32 + rc) * KPAD;
  const ushort16* b1   = b0 + (size_t)16 * KPAD;

  for (int s = s0; s < s1; ++s) {
    int k = s * 32 + kq * 8;
    bf16x8 a  = *(const bf16x8*)(arow + k);
    bf16x8 v0 = *(const bf16x8*)(b0 + k);
    bf16x8 v1 = *(const bf16x8*)(b1 + k);
    acc0 = __builtin_amdgcn_mfma_f32_16x16x32_bf16(a, v0, acc0, 0, 0, 0);
    acc1 = __builtin_amdgcn_mfma_f32_16x16x32_bf16(a, v1, acc1, 0, 0, 0);
  }

  float* dst = Rtmp8 + (size_t)kc * (NREG * CHAN);
  int orow = m0 + kq * 4;
#pragma unroll
  for (int r = 0; r < 4; ++r) {
    int gr = orow + r;
    if (gr < NREG) {
      dst[(size_t)gr * CHAN + wid * 32 + rc]      = acc0[r];
      dst[(size_t)gr * CHAN + wid * 32 + 16 + rc] = acc1[r];
    }
  }
}

// Rf = 0.8*Rf + 0.2*sum(Rtmp8 slices) ; mirror region rows into bf16 gather table
__global__ void k_region_apply(float* __restrict__ Rf, const float* __restrict__ Rtmp8,
                               ushort16* __restrict__ curB) {
  int i = blockIdx.x * blockDim.x + threadIdx.x;
  if (i < NREG * CHAN) {
    float t = 0.f;
#pragma unroll
    for (int c = 0; c < NKC2; ++c) t += Rtmp8[(size_t)c * (NREG * CHAN) + i];
    float v = Rf[i] * 0.8f + t * 0.2f;
    Rf[i] = v;
    curB[(size_t)REG0 * CHAN + i] = (ushort16)f2bf(v);
  }
}

// ---------------- fused agg: entity + user waves, depth-2 pipeline ----------------
// Fixed-stride maskless CSR: pk[h*64 + slot], deg[h]; pk batch load bounded by the
// padded degree (no useless line fetches). nch <= 16 -> no batch refresh, shuffle
// slot = (chunk<<2)|e always valid. Depth-2 unrolled-by-2 ping-pong: chunks ci and
// ci+1 in flight while consuming -> 6 outstanding gathers/wave (was 3). No register
// rotation moves (A/B alternate roles via unroll). Sentinel padding (rel=25 zero
// weight row / val=0) keeps consume maskless. l2norm is scale-invariant -> no
// inv_deg. All shuffles UNCONDITIONAL within wave-uniform branches.

__global__ __launch_bounds__(256) void k_agg(
    const ushort16* __restrict__ curB,
    const int* __restrict__ edeg, const int* __restrict__ epk,
    const float* __restrict__ Wt,
    uint32* __restrict__ nxtB, float* __restrict__ nxtRf, float* __restrict__ out_e,
    const int* __restrict__ udeg, const int2* __restrict__ upk,
    float* __restrict__ out_u) {
  int bid  = blockIdx.x;
  int wid  = threadIdx.x >> 6;
  int lane = threadIdx.x & 63;
  int grp  = bid % 3;
  int trip = bid / 3;
  int e = lane >> 4;
  int q = lane & 15;

  if (grp < 2) {
    // ---------------- entity wave ----------------
    int h = trip * 8 + grp * 4 + wid;            // < 100000
    int nch = (edeg[h] + 3) >> 2;
    int pd  = nch << 2;                          // == padded degree
    int pkv = 0;
    if (lane < pd) pkv = epk[(size_t)h * PKSTR + lane];   // only useful lines fetched

    float acc[8];
#pragma unroll
    for (int k = 0; k < 8; ++k) acc[k] = 0.f;

    uint4  evA, evB;
    float4 waA, wbA, waB, wbB;

#define E_ISS(CN, EV, WA, WB) do {                                            \
    int _p = __shfl(pkv, ((CN) << 2) | e, 64);                                \
    int _t = _p & 0x1FFFF;                                                    \
    int _r = _p >> 17;                                                        \
    EV = *(const uint4*)((const char*)curB + ((size_t)_t << 8) + (q << 4));   \
    const float* _wr = Wt + ((size_t)_r << 7) + (q << 3);                     \
    WA = *(const float4*)_wr;                                                 \
    WB = *(const float4*)(_wr + 4);                                           \
  } while (0)

#define E_CONS(EV, WA, WB) do {            \
    acc[0] += bf_lo(EV.x) * WA.x;          \
    acc[1] += bf_hi(EV.x) * WA.y;          \
    acc[2] += bf_lo(EV.y) * WA.z;          \
    acc[3] += bf_hi(EV.y) * WA.w;          \
    acc[4] += bf_lo(EV.z) * WB.x;          \
    acc[5] += bf_hi(EV.z) * WB.y;          \
    acc[6] += bf_lo(EV.w) * WB.z;          \
    acc[7] += bf_hi(EV.w) * WB.w;          \
  } while (0)

    E_ISS(0, evA, waA, wbA);                 // safe even when nch==0 (pkv=0 -> row 0)
    if (1 < nch) E_ISS(1, evB, waB, wbB);
    for (int ci = 0; ci < nch; ci += 2) {
      E_CONS(evA, waA, wbA);
      if (ci + 2 < nch) E_ISS(ci + 2, evA, waA, wbA);
      if (ci + 1 < nch) {
        E_CONS(evB, waB, wbB);
        if (ci + 3 < nch) E_ISS(ci + 3, evB, waB, wbB);
      }
    }
#undef E_ISS
#undef E_CONS

#pragma unroll
    for (int k = 0; k < 8; ++k) {
      acc[k] += __shfl_xor(acc[k], 16, 64);
      acc[k] += __shfl_xor(acc[k], 32, 64);
    }
    float ss = 0.f;
#pragma unroll
    for (int k = 0; k < 8; ++k) ss += acc[k] * acc[k];
#pragma unroll
    for (int off = 8; off; off >>= 1) ss += __shfl_xor(ss, off, 64);
    float inv = 1.0f / fmaxf(sqrtf(ss), 1e-12f);
#pragma unroll
    for (int k = 0; k < 8; ++k) acc[k] *= inv;

    if (e == 0) {   // 16 lanes cover the full 128-channel row
      uint4 bpk;
      bpk.x = f2bf(acc[0]) | (f2bf(acc[1]) << 16);
      bpk.y = f2bf(acc[2]) | (f2bf(acc[3]) << 16);
      bpk.z = f2bf(acc[4]) | (f2bf(acc[5]) << 16);
      bpk.w = f2bf(acc[6]) | (f2bf(acc[7]) << 16);
      *(uint4*)((char*)nxtB + ((size_t)h << 8) + (q << 4)) = bpk;
      if (h >= REG0 && h < REG0 + NREG) {
        float* rp = nxtRf + ((size_t)(h - REG0) << 7) + (q << 3);
        *(float4*)rp       = make_float4(acc[0], acc[1], acc[2], acc[3]);
        *(float4*)(rp + 4) = make_float4(acc[4], acc[5], acc[6], acc[7]);
      }
      float* op = out_e + ((size_t)h << 7) + (q << 3);
      float4 o0 = *(const float4*)op;
      float4 o1 = *(const float4*)(op + 4);
      o0.x += acc[0]; o0.y += acc[1]; o0.z += acc[2]; o0.w += acc[3];
      o1.x += acc[4]; o1.y += acc[5]; o1.z += acc[6]; o1.w += acc[7];
      *(float4*)op       = o0;
      *(float4*)(op + 4) = o1;
    }
  } else {
    // ---------------- user wave ----------------
    int u = trip * 4 + wid;                     // < 50000
    int nch = (udeg[u] + 3) >> 2;
    int pd  = nch << 2;
    int2 pkv = make_int2(0, 0);
    if (lane < pd) pkv = upk[(size_t)u * PKSTR + lane];

    float acc[8];
#pragma unroll
    for (int k = 0; k < 8; ++k) acc[k] = 0.f;

    uint4 evA, evB;
    float vA, vB;

#define U_ISS(CN, EV, V) do {                                                 \
    int _sl = ((CN) << 2) | e;                                                \
    int _c = __shfl(pkv.x, _sl, 64);                                          \
    V = __int_as_float(__shfl(pkv.y, _sl, 64));                               \
    EV = *(const uint4*)((const char*)curB + ((size_t)_c << 8) + (q << 4));   \
  } while (0)

#define U_CONS(EV, V) do {          \
    acc[0] += V * bf_lo(EV.x);      \
    acc[1] += V * bf_hi(EV.x);      \
    acc[2] += V * bf_lo(EV.y);      \
    acc[3] += V * bf_hi(EV.y);      \
    acc[4] += V * bf_lo(EV.z);      \
    acc[5] += V * bf_hi(EV.z);      \
    acc[6] += V * bf_lo(EV.w);      \
    acc[7] += V * bf_hi(EV.w);      \
  } while (0)

    U_ISS(0, evA, vA);
    if (1 < nch) U_ISS(1, evB, vB);
    for (int ci = 0; ci < nch; ci += 2) {
      U_CONS(evA, vA);
      if (ci + 2 < nch) U_ISS(ci + 2, evA, vA);
      if (ci + 1 < nch) {
        U_CONS(evB, vB);
        if (ci + 3 < nch) U_ISS(ci + 3, evB, vB);
      }
    }
#undef U_ISS
#undef U_CONS

#pragma unroll
    for (int k = 0; k < 8; ++k) {
      acc[k] += __shfl_xor(acc[k], 16, 64);
      acc[k] += __shfl_xor(acc[k], 32, 64);
    }
    float ss = 0.f;
#pragma unroll
    for (int k = 0; k < 8; ++k) ss += acc[k] * acc[k];
#pragma unroll
    for (int off = 8; off; off >>= 1) ss += __shfl_xor(ss, off, 64);
    float inv = 1.0f / fmaxf(sqrtf(ss), 1e-12f);
#pragma unroll
    for (int k = 0; k < 8; ++k) acc[k] *= inv;

    if (e == 0) {
      float* op = out_u + ((size_t)u << 7) + (q << 3);
      float4 o0 = *(const float4*)op;
      float4 o1 = *(const float4*)(op + 4);
      o0.x += acc[0]; o0.y += acc[1]; o0.z += acc[2]; o0.w += acc[3];
      o1.x += acc[4]; o1.y += acc[5]; o1.z += acc[6]; o1.w += acc[7];
      *(float4*)op       = o0;
      *(float4*)(op + 4) = o1;
    }
  }
}

// ---------------- launch ----------------

extern "C" void kernel_launch(void* const* d_in, const int* in_sizes, int n_in,
                              void* d_out, int out_size, void* d_ws, size_t ws_size,
                              hipStream_t stream) {
  const float* user_emb   = (const float*)d_in[0];
  const float* entity_emb = (const float*)d_in[1];
  const float* RW         = (const float*)d_in[2];
  const float* weight     = (const float*)d_in[3];
  const float* ivals      = (const float*)d_in[4];
  const int*   e_head     = (const int*)d_in[5];
  const int*   e_tail     = (const int*)d_in[6];
  const int*   e_type     = (const int*)d_in[7];
  const int*   i_rows     = (const int*)d_in[8];
  const int*   i_cols     = (const int*)d_in[9];

  float* out_e = (float*)d_out;                        // [N_ENT, 128]
  float* out_u = (float*)d_out + (size_t)N_ENT * CHAN; // [N_USR, 128]

  char* p = (char*)d_ws;
  size_t off = 0;
  auto carve = [&](size_t bytes) -> void* {
    void* r = p + off;
    off += (bytes + 255) & ~(size_t)255;
    return r;
  };
  ushort16* B16a   = (ushort16*)carve((size_t)N_ENT * CHAN * 2);
  ushort16* B16b   = (ushort16*)carve((size_t)N_ENT * CHAN * 2);
  ushort16* RWb    = (ushort16*)carve((size_t)MPAD * KPAD * 2);   // 13.7 MB bf16 weights
  ushort16* RbT    = (ushort16*)carve((size_t)CHAN * KPAD * 2);   // transposed bf16 X
  float* Rfa       = (float*)carve((size_t)NREG * CHAN * 4);
  float* Rfb       = (float*)carve((size_t)NREG * CHAN * 4);
  float* wt26      = (float*)carve((size_t)26 * CHAN * 4);
  int*   e_deg     = (int*)carve((size_t)N_ENT * 4);
  int*   u_deg     = (int*)carve((size_t)N_USR * 4);
  int*   e_pk      = (int*)carve((size_t)N_ENT * PKSTR * 4);      // 25.6 MB
  int2*  u_pk      = (int2*)carve((size_t)N_USR * PKSTR * 8);     // 25.6 MB
  // shared region: CSR staging slab (build phase) OVERLAYS Rtmp8 (hop phase)
  size_t st_bytes   = (size_t)NB_E * BCAP * 4 > (size_t)NB_U * BCAP * 8
                      ? (size_t)NB_E * BCAP * 4 : (size_t)NB_U * BCAP * 8;
  size_t rtmp_bytes = (size_t)NKC2 * NREG * CHAN * 4;
  char*  shared_rg = (char*)carve(st_bytes > rtmp_bytes ? st_bytes : rtmp_bytes);
  float* Rtmp8     = (float*)shared_rg;
  int*   e_bcur    = (int*)carve((size_t)NB_E * 4);   // adjacent: one memset covers
  int*   u_bcur    = (int*)carve((size_t)NB_U * 4);   // both (e pads to 1024B)
  if (off > ws_size) return;

  // ---- CSR builds (bucketed multisplit, fixed-stride maskless segments) ----
  hipMemsetAsync(e_bcur, 0, 1024 + (size_t)NB_U * 4, stream);   // e_bcur + u_bcur
  k_part_e<<<NWG_E, 256, 0, stream>>>(e_head, e_tail, e_type, e_bcur, (uint32*)shared_rg);
  k_place_e<<<NB_E, 512, 0, stream>>>((const uint32*)shared_rg, e_bcur, e_deg, e_pk);
  k_part_u<<<NWG_U, 256, 0, stream>>>(i_rows, i_cols, ivals, u_bcur, (uint2*)shared_rg);
  k_place_u<<<NB_U, 512, 0, stream>>>((const uint2*)shared_rg, u_bcur, u_deg, u_pk);

  // ---- fused init ----
  k_init<<<G_INIT, 256, 0, stream>>>(RW, (uint32*)RWb, weight, wt26,
                                     entity_emb, (uint32*)B16a, out_e, Rfa,
                                     user_emb, out_u);

  // ---- 3 hops ----
  for (int hop = 0; hop < 3; ++hop) {
    ushort16* curB = (hop & 1) ? B16b : B16a;
    ushort16* nxtB = (hop & 1) ? B16a : B16b;
    float*    curR = (hop & 1) ? Rfb : Rfa;
    float*    nxtR = (hop & 1) ? Rfa : Rfb;
    k_build_rbt<<<(CHAN * (KPAD / 8) + 255) / 256, 256, 0, stream>>>(curR, (uint32*)RbT);
    k_region_mfma<<<MT16 * NKC2, 256, 0, stream>>>(RWb, RbT, Rtmp8);
    k_region_apply<<<(NREG * CHAN + 255) / 256, 256, 0, stream>>>(curR, Rtmp8, curB);
    k_agg<<<NBLK_AGG, 256, 0, stream>>>(curB, e_deg, e_pk, wt26,
                                        (uint32*)nxtB, nxtR, out_e,
                                        u_deg, u_pk, out_u);
  }
}